// Round 9
// baseline (161.329 us; speedup 1.0000x reference)
//
#include <hip/hip_runtime.h>

// Split implementation for MI355X (gfx950).
// K1: per-batch 512-bin voxel histogram (v4 dense+LDS-staged structure,
//     byte-identical binning math) -> u32 counts in d_ws (1024 x 512).
// K2: counts @ W^T + bias with W staged transposed in LDS (conflict-free
//     stride-40 reads), accumulation order bit-identical to the passing
//     fused epilogue (4 partials per class, ((a0+a1)+(a2+a3)), *1/N, +bias).

#define VR        8
#define BINS      512      // VR^3
#define CLASSES   40
#define NPTS      8192

// ---------------- kernel 1: histogram ----------------
#define T1        512
#define CHUNK_PTS 2048
#define CHUNK_F4  1536     // 2048 pts * 12B / 16
#define NCHUNK    4

__global__ __launch_bounds__(T1, 8) void hist_kernel(
    const float* __restrict__ x, unsigned int* __restrict__ Hc)
{
    __shared__ float xs[CHUNK_PTS * 3];      // 24 KB
    __shared__ unsigned int hist[BINS];      // 2 KB
    const int t = threadIdx.x;
    const int b = blockIdx.x;

    hist[t] = 0u;                            // T1 == BINS

    const float4* px = (const float4*)(x + (size_t)b * NPTS * 3);
    float4* xsv = (float4*)xs;

    float4 r0 = px[t];
    float4 r1 = px[t + 512];
    float4 r2 = px[t + 1024];

    for (int c = 0; c < NCHUNK; ++c) {
        __syncthreads();
        xsv[t]        = r0;
        xsv[t + 512]  = r1;
        xsv[t + 1024] = r2;
        if (c + 1 < NCHUNK) {
            const float4* ns = px + (c + 1) * CHUNK_F4;
            r0 = ns[t]; r1 = ns[t + 512]; r2 = ns[t + 1024];
        }
        __syncthreads();

        #pragma unroll
        for (int k = 0; k < 4; ++k) {
            const int p = k * T1 + t;
            const float vx = xs[p * 3 + 0];
            const float vy = xs[p * 3 + 1];
            const float vz = xs[p * 3 + 2];
            const bool ok = (__builtin_fabsf(vx) <= 2.f) &&
                            (__builtin_fabsf(vy) <= 2.f) &&
                            (__builtin_fabsf(vz) <= 2.f);
            // exact reference rounding: (v+2)*2 exact in fp32, trunc==floor,
            // clamp 8 -> 7 (v == HI); out-of-range gated by ok
            const int ix = min((int)((vx + 2.f) * 2.f), VR - 1);
            const int iy = min((int)((vy + 2.f) * 2.f), VR - 1);
            const int iz = min((int)((vz + 2.f) * 2.f), VR - 1);
            if (ok) atomicAdd(&hist[(ix * VR + iy) * VR + iz], 1u);
        }
    }
    __syncthreads();
    Hc[(size_t)b * BINS + t] = hist[t];      // coalesced 2 KB store
}

// ---------------- kernel 2: counts @ W^T + bias ----------------
// grid 256 x 256thr; block = 4 waves = 4 batch rows. LDS: half of W
// transposed wt[v][c] (stride 40 words -> lanes c=0..39 hit distinct
// banks) + 4 converted H rows. Two v-halves reuse the 40 KB wt buffer.
#define T2 256

__global__ __launch_bounds__(T2, 1) void matvec_kernel(
    const unsigned int* __restrict__ Hc,
    const float* __restrict__ W,
    const float* __restrict__ bias,
    float* __restrict__ out)
{
    __shared__ float wt[256][CLASSES];   // 40 KB: wt[v_local][c] = W[c][v]
    __shared__ float hs[4][BINS];        // 8 KB: converted counts
    const int t = threadIdx.x;
    const int w = t >> 6;                // wave id 0..3
    const int l = t & 63;                // lane
    const int r = blockIdx.x * 4 + w;    // batch row 0..1023

    // stage this wave's H row, u32 -> f32 (exact: counts <= 8192)
    {
        const uint4* h4 = (const uint4*)(Hc + (size_t)r * BINS);
        float4* hv = (float4*)hs[w];
        #pragma unroll
        for (int k = 0; k < 2; ++k) {
            const uint4 u = h4[l + 64 * k];
            float4 f;
            f.x = (float)u.x; f.y = (float)u.y;
            f.z = (float)u.z; f.w = (float)u.w;
            hv[l + 64 * k] = f;
        }
    }

    const int c = l;                     // lane = class (lanes 40..63 idle)
    float a0 = 0.f, a1 = 0.f, a2 = 0.f, a3 = 0.f;

    for (int h = 0; h < 2; ++h) {
        __syncthreads();                 // hs visible / wt safe to overwrite
        // stage wt[vl][c] = W[c][vl + 256h]; 2560 tasks = 10 per thread
        #pragma unroll
        for (int i = 0; i < 10; ++i) {
            const int j  = t + i * T2;   // 0..2559
            const int vl = j / 10;
            const int q  = j % 10;
            const int v  = vl + 256 * h;
            #pragma unroll
            for (int k = 0; k < 4; ++k)
                wt[vl][4 * q + k] = W[(4 * q + k) * BINS + v];
        }
        __syncthreads();

        if (c < CLASSES) {
            // identical accumulation order to the passing fused epilogue:
            // a_s = sum_i cnt[4i+s] * W[c][4i+s], i increasing
            #pragma unroll 4
            for (int i = 0; i < 64; ++i) {
                const int v0 = 4 * i;
                const int g0 = 256 * h + v0;
                a0 += hs[w][g0 + 0] * wt[v0 + 0][c];
                a1 += hs[w][g0 + 1] * wt[v0 + 1][c];
                a2 += hs[w][g0 + 2] * wt[v0 + 2][c];
                a3 += hs[w][g0 + 3] * wt[v0 + 3][c];
            }
        }
    }

    if (c < CLASSES) {
        const float acc = ((a0 + a1) + (a2 + a3));   // same tree as shfl version
        out[r * CLASSES + c] = acc * (1.0f / NPTS) + bias[c];
    }
}

extern "C" void kernel_launch(void* const* d_in, const int* in_sizes, int n_in,
                              void* d_out, int out_size, void* d_ws, size_t ws_size,
                              hipStream_t stream) {
    const float* x    = (const float*)d_in[0];   // (1024, 8192, 3)
    const float* W    = (const float*)d_in[1];   // (40, 512)
    const float* bias = (const float*)d_in[2];   // (40,)
    float* out        = (float*)d_out;           // (1024, 40)
    unsigned int* Hc  = (unsigned int*)d_ws;     // (1024, 512) u32 counts

    const int nbatch = in_sizes[0] / (NPTS * 3); // 1024
    hist_kernel  <<<nbatch,     T1, 0, stream>>>(x, Hc);
    matvec_kernel<<<nbatch / 4, T2, 0, stream>>>(Hc, W, bias, out);
}

// Round 12
// 152.898 us; speedup vs baseline: 1.0551x; 1.0551x over previous
//
#include <hip/hip_runtime.h>

// Fused voxel-histogram + linear classifier for MI355X (gfx950).
// v6: 8x lane-interleaved replicated sub-histograms to attack LDS-atomic
// serialization (the measured ~32us residual: v1=v2=v4=K1-alone=48us, all
// sharing only the ds_add inner loop; stream floor is 16us).
// histr word = bin*8 + (lane&7): same-bin lanes -> different banks.
// Merge (2x ds_read_b128 + 7 adds) then the byte-identical fused epilogue.

#define VR      8
#define BINS    512      // VR^3
#define CLASSES 40
#define NPTS    8192
#define THREADS 512
#define NCOPY   8
#define NGROUPS 4        // 16 pts/thread = 4 groups of 4 points (3 float4 each)

__global__ __launch_bounds__(THREADS, 8) void voxel_cls_kernel(
    const float* __restrict__ x,
    const float* __restrict__ W,
    const float* __restrict__ bias,
    float* __restrict__ out)
{
    __shared__ unsigned int histr[BINS * NCOPY];  // 16 KB replicated
    __shared__ unsigned int hist[BINS];           // 2 KB merged
    const int t = threadIdx.x;
    const int b = blockIdx.x;
    const int r = t & (NCOPY - 1);                // sub-histogram id

    // zero 4096 words / 512 threads: word t+512i -> bank t%32, 2-way, free
    #pragma unroll
    for (int i = 0; i < NCOPY; ++i) histr[t + i * THREADS] = 0u;
    __syncthreads();

    // ---- histogram phase (v2 strided loads; proved equal to staged) ----
    const float4* px = (const float4*)(x + (size_t)b * NPTS * 3);
    #pragma unroll 2
    for (int g = 0; g < NGROUPS; ++g) {
        const int base = (g * THREADS + t) * 3;
        const float4 A = px[base + 0];
        const float4 B = px[base + 1];
        const float4 C = px[base + 2];

        const float qx[4] = {A.x, A.w, B.z, C.y};
        const float qy[4] = {A.y, B.x, B.w, C.z};
        const float qz[4] = {A.z, B.y, C.x, C.w};

        #pragma unroll
        for (int p = 0; p < 4; ++p) {
            const float vx = qx[p], vy = qy[p], vz = qz[p];
            const bool ok = (__builtin_fabsf(vx) <= 2.f) &&
                            (__builtin_fabsf(vy) <= 2.f) &&
                            (__builtin_fabsf(vz) <= 2.f);
            // exact reference rounding: (v+2)*2 exact in fp32, trunc==floor,
            // clamp 8 -> 7 (v == HI in last bin); out-of-range gated by ok
            const int ix = min((int)((vx + 2.f) * 2.f), VR - 1);
            const int iy = min((int)((vy + 2.f) * 2.f), VR - 1);
            const int iz = min((int)((vz + 2.f) * 2.f), VR - 1);
            if (ok) {
                const int lin = (ix * VR + iy) * VR + iz;
                atomicAdd(&histr[lin * NCOPY + r], 1u);
            }
        }
    }
    __syncthreads();

    // ---- merge: hist[t] = sum of 8 replicas of bin t ----
    {
        const uint4* h4 = (const uint4*)(histr + t * NCOPY);
        const uint4 u0 = h4[0];
        const uint4 u1 = h4[1];
        hist[t] = ((u0.x + u0.y) + (u0.z + u0.w)) +
                  ((u1.x + u1.y) + (u1.z + u1.w));
    }
    __syncthreads();

    // ---- epilogue (byte-identical to the absmax=0 kernels) ----
    if (t < CLASSES * 4) {
        const int c = t >> 2;
        const int s = t & 3;
        const float* Wc = W + c * BINS;
        float acc = 0.f;
        #pragma unroll 8
        for (int i = 0; i < BINS / 4; ++i) {
            const int v = i * 4 + s;
            acc += (float)hist[v] * Wc[v];
        }
        acc += __shfl_xor(acc, 1);
        acc += __shfl_xor(acc, 2);
        if (s == 0)
            out[b * CLASSES + c] = acc * (1.0f / NPTS) + bias[c];
    }
}

extern "C" void kernel_launch(void* const* d_in, const int* in_sizes, int n_in,
                              void* d_out, int out_size, void* d_ws, size_t ws_size,
                              hipStream_t stream) {
    const float* x    = (const float*)d_in[0];   // (1024, 8192, 3)
    const float* W    = (const float*)d_in[1];   // (40, 512)
    const float* bias = (const float*)d_in[2];   // (40,)
    float* out        = (float*)d_out;           // (1024, 40)

    const int nbatch = in_sizes[0] / (NPTS * 3); // 1024
    voxel_cls_kernel<<<nbatch, THREADS, 0, stream>>>(x, W, bias, out);
}